// Round 2
// baseline (206.539 us; speedup 1.0000x reference)
//
#include <hip/hip_runtime.h>

#define N_GAUSS 1024
#define H_DIM 768
#define W_DIM 768

typedef float v2f __attribute__((ext_vector_type(2)));

// Per-gaussian packed params in workspace: {mx, my, A, Bc, D, wr, wg, wb}
// exponent for exp2: A*dx^2 + Bc*dx*dy + D*dy^2  (the -0.5*log2(e) factor is
// folded into A/Bc/D so the hot loop is a single v_exp_f32 per pixel).

__global__ __launch_bounds__(256) void prep_kernel(
    const float* __restrict__ means, const float* __restrict__ covs,
    const float* __restrict__ colors, float* __restrict__ gp) {
  int n = blockIdx.x * 256 + threadIdx.x;
  if (n >= N_GAUSS) return;
  float mx = means[n * 2 + 0];
  float my = means[n * 2 + 1];
  float a = covs[n * 4 + 0];
  float b = covs[n * 4 + 1];
  float c = covs[n * 4 + 2];
  float d = covs[n * 4 + 3];
  float inv = 1.0f / (a * d - b * c);
  const float L = -0.72134752044448170368f;  // -0.5 * log2(e)
  float A  = L * d * inv;          // L * ia
  float Bc = -L * (b + c) * inv;   // L * (ib + ic)
  float D  = L * a * inv;          // L * id
  float cr = colors[n * 4 + 0];
  float cg = colors[n * 4 + 1];
  float cb = colors[n * 4 + 2];
  float al = colors[n * 4 + 3];
  // weighted rgb = sigmoid(c) * alpha  (alpha NOT sigmoided)
  float wr = al / (1.0f + expf(-cr));
  float wg = al / (1.0f + expf(-cg));
  float wb = al / (1.0f + expf(-cb));
  float* g = gp + n * 8;
  g[0] = mx; g[1] = my; g[2] = A; g[3] = Bc; g[4] = D;
  g[5] = wr; g[6] = wg; g[7] = wb;
}

// 2 pixels per thread (w, w+128), packed fp32 (v_pk_fma_f32) for the pair.
// 128-thread blocks x 2304 = 9 blocks/CU exactly, 18 waves/CU.
// h is workgroup-uniform -> gaussian param loads scalarize to s_load;
// per-gaussian float prep (dx/qa/qb) is VALU (SALU has no FP).
__global__ __launch_bounds__(128) void render_kernel(
    const float* __restrict__ gp, float* __restrict__ out) {
  const int h   = blockIdx.x / 3;        // row, block-uniform
  const int seg = blockIdx.x % 3;        // 256-px segment within the row
  const int t   = threadIdx.x;           // 0..127
  const int w0  = seg * 256 + t;
  const int w1  = w0 + 128;

  const float scale = 1.0f / 767.0f;     // linspace(0,1,768) step
  const float x = (float)h * scale;
  const v2f ypair = {(float)w0 * scale, (float)w1 * scale};

  v2f rg0 = {0.f, 0.f};   // (r,g) of pixel 0
  v2f rg1 = {0.f, 0.f};   // (r,g) of pixel 1
  v2f bb  = {0.f, 0.f};   // (b of px0, b of px1)

#pragma unroll 4
  for (int n = 0; n < N_GAUSS; ++n) {
    const float* g = gp + n * 8;
    const float mx = g[0], my = g[1], A = g[2], Bc = g[3], D = g[4];
    const v2f   wrg = {g[5], g[6]};
    const float wb  = g[7];

    // per-gaussian (block-uniform values, but VALU ops)
    const float dx = x - mx;
    const float qa = A * dx * dx;
    const float qb = Bc * dx;

    // packed pixel-pair math
    v2f dy = ypair - (v2f){my, my};
    v2f q  = __builtin_elementwise_fma((v2f){D, D}, dy, (v2f){qb, qb});
    q      = __builtin_elementwise_fma(q, dy, (v2f){qa, qa});

    const float v0 = __builtin_amdgcn_exp2f(q[0]);
    const float v1 = __builtin_amdgcn_exp2f(q[1]);

    rg0 = __builtin_elementwise_fma((v2f){v0, v0}, wrg, rg0);
    rg1 = __builtin_elementwise_fma((v2f){v1, v1}, wrg, rg1);
    bb  = __builtin_elementwise_fma((v2f){v0, v1}, (v2f){wb, wb}, bb);
  }

  float* o0 = out + ((size_t)h * W_DIM + w0) * 3;
  o0[0] = rg0[0]; o0[1] = rg0[1]; o0[2] = bb[0];
  float* o1 = out + ((size_t)h * W_DIM + w1) * 3;
  o1[0] = rg1[0]; o1[1] = rg1[1]; o1[2] = bb[1];
}

extern "C" void kernel_launch(void* const* d_in, const int* in_sizes, int n_in,
                              void* d_out, int out_size, void* d_ws, size_t ws_size,
                              hipStream_t stream) {
  const float* means  = (const float*)d_in[0];   // (N,2,1)
  const float* covs   = (const float*)d_in[1];   // (N,2,2)
  const float* colors = (const float*)d_in[2];   // (N,4)
  float* gp = (float*)d_ws;                      // N*8 floats = 32 KB
  float* out = (float*)d_out;                    // (768,768,3) fp32

  prep_kernel<<<dim3(N_GAUSS / 256), dim3(256), 0, stream>>>(means, covs, colors, gp);
  render_kernel<<<dim3((H_DIM * W_DIM) / (128 * 2)), dim3(128), 0, stream>>>(gp, out);
}

// Round 3
// 163.913 us; speedup vs baseline: 1.2600x; 1.2600x over previous
//
#include <hip/hip_runtime.h>

#define N_GAUSS 1024
#define H_DIM 768
#define W_DIM 768

typedef float v2f __attribute__((ext_vector_type(2)));

// gpa[n] = {mx, my, A, Bc}; gpb[n] = {D, wr, wg, wb}
// A, Bc, D carry the -0.5*log2(e) factor so the hot loop uses raw exp2.
__global__ __launch_bounds__(256) void prep_kernel(
    const float* __restrict__ means, const float* __restrict__ covs,
    const float* __restrict__ colors, float4* __restrict__ gpa,
    float4* __restrict__ gpb) {
  int n = blockIdx.x * 256 + threadIdx.x;
  if (n >= N_GAUSS) return;
  float mx = means[n * 2 + 0];
  float my = means[n * 2 + 1];
  float a = covs[n * 4 + 0];
  float b = covs[n * 4 + 1];
  float c = covs[n * 4 + 2];
  float d = covs[n * 4 + 3];
  float inv = 1.0f / (a * d - b * c);
  const float L = -0.72134752044448170368f;  // -0.5 * log2(e)
  float A  = L * d * inv;
  float Bc = -L * (b + c) * inv;
  float D  = L * a * inv;
  float cr = colors[n * 4 + 0];
  float cg = colors[n * 4 + 1];
  float cb = colors[n * 4 + 2];
  float al = colors[n * 4 + 3];
  float wr = al / (1.0f + expf(-cr));
  float wg = al / (1.0f + expf(-cg));
  float wb = al / (1.0f + expf(-cb));
  gpa[n] = make_float4(mx, my, A, Bc);
  gpb[n] = make_float4(D, wr, wg, wb);
}

// One block per (row, 256-px segment). Per-row quadratic-in-y coefficients
// {c1,c0} are computed once per block into LDS (8 KB), so the hot loop is:
//   q = (D*y + c1)*y + c0; v = exp2(q); rgb += v*w
// = 2 pk_fma + 2 exp + 3 pk_fma per gaussian per 2 pixels.
__global__ __launch_bounds__(128) void render_kernel(
    const float4* __restrict__ gpa, const float4* __restrict__ gpb,
    float* __restrict__ out) {
  __shared__ v2f cc[N_GAUSS];  // {c1, c0} per gaussian for this row

  const int h   = blockIdx.x / 3;
  const int seg = blockIdx.x % 3;
  const int t   = threadIdx.x;  // 0..127
  const float scale = 1.0f / 767.0f;
  const float x = (float)h * scale;

  // Block-level coefficient prep: 8 gaussians per thread.
#pragma unroll
  for (int i = 0; i < N_GAUSS / 128; ++i) {
    int n = i * 128 + t;
    float4 p = gpa[n];                 // mx, my, A, Bc
    float D = gpb[n].x;
    float dx = x - p.x;
    float qa = p.z * dx * dx;          // A*dx^2
    float qb = p.w * dx;               // Bc*dx
    float c1 = fmaf(-2.0f * D, p.y, qb);
    float c0 = fmaf(fmaf(D, p.y, -qb), p.y, qa);
    cc[n] = (v2f){c1, c0};
  }
  __syncthreads();

  const int w0 = seg * 256 + t;
  const int w1 = w0 + 128;
  const v2f y = {(float)w0 * scale, (float)w1 * scale};

  v2f rg0 = {0.f, 0.f};
  v2f rg1 = {0.f, 0.f};
  v2f bb  = {0.f, 0.f};

#pragma unroll 8
  for (int n = 0; n < N_GAUSS; ++n) {
    const v2f k = cc[n];               // broadcast ds_read (conflict-free)
    const float4 s = gpb[n];           // uniform -> s_load_dwordx4

    v2f q = __builtin_elementwise_fma((v2f){s.x, s.x}, y, (v2f){k.x, k.x});
    q     = __builtin_elementwise_fma(q, y, (v2f){k.y, k.y});

    const float v0 = __builtin_amdgcn_exp2f(q.x);
    const float v1 = __builtin_amdgcn_exp2f(q.y);

    const v2f wrg = {s.y, s.z};
    rg0 = __builtin_elementwise_fma((v2f){v0, v0}, wrg, rg0);
    rg1 = __builtin_elementwise_fma((v2f){v1, v1}, wrg, rg1);
    bb  = __builtin_elementwise_fma((v2f){v0, v1}, (v2f){s.w, s.w}, bb);
  }

  float* o0 = out + ((size_t)h * W_DIM + w0) * 3;
  o0[0] = rg0.x; o0[1] = rg0.y; o0[2] = bb.x;
  float* o1 = out + ((size_t)h * W_DIM + w1) * 3;
  o1[0] = rg1.x; o1[1] = rg1.y; o1[2] = bb.y;
}

extern "C" void kernel_launch(void* const* d_in, const int* in_sizes, int n_in,
                              void* d_out, int out_size, void* d_ws, size_t ws_size,
                              hipStream_t stream) {
  const float* means  = (const float*)d_in[0];   // (N,2,1)
  const float* covs   = (const float*)d_in[1];   // (N,2,2)
  const float* colors = (const float*)d_in[2];   // (N,4)
  float4* gpa = (float4*)d_ws;                   // 16 KB
  float4* gpb = gpa + N_GAUSS;                   // 16 KB
  float* out = (float*)d_out;                    // (768,768,3) fp32

  prep_kernel<<<dim3(N_GAUSS / 256), dim3(256), 0, stream>>>(
      means, covs, colors, gpa, gpb);
  render_kernel<<<dim3((H_DIM * W_DIM) / (128 * 2)), dim3(128), 0, stream>>>(
      gpa, gpb, out);
}